// Round 1
// baseline (231.079 us; speedup 1.0000x reference)
//
#include <hip/hip_runtime.h>
#include <hip/hip_bf16.h>

// B=2, T=2048, C=1024, H=16, D=64
#define TB 2048
#define CC 1024
#define HH 16
#define DD 64
#define MM 4096     // B*T
#define N3 3072     // 3*C

typedef __bf16 bf16x8 __attribute__((ext_vector_type(8)));
typedef float f32x4 __attribute__((ext_vector_type(4)));
typedef unsigned short ushort8 __attribute__((ext_vector_type(8)));
typedef unsigned short u16;

__device__ __forceinline__ u16 f2b(float f) {
    unsigned int x = __float_as_uint(f);
    x = (x + 0x7fffu + ((x >> 16) & 1u)) >> 16;
    return (u16)x;
}

// ---------- fp32 -> bf16 convert (vectorized) ----------
__global__ __launch_bounds__(256) void cvt_bf16(const float* __restrict__ in,
                                                u16* __restrict__ out, int n) {
    int i = (blockIdx.x * 256 + threadIdx.x) * 4;
    if (i >= n) return;
    float4 v = *reinterpret_cast<const float4*>(in + i);
    union { u16 u[4]; uint2 v2; } r;
    r.u[0] = f2b(v.x); r.u[1] = f2b(v.y); r.u[2] = f2b(v.z); r.u[3] = f2b(v.w);
    *reinterpret_cast<uint2*>(out + i) = r.v2;
}

// ---------- fp32 [K][N] -> bf16 [N][K] (tiled transpose) ----------
__global__ __launch_bounds__(256) void transpose_cvt(const float* __restrict__ in,
                                                     u16* __restrict__ out,
                                                     int K, int N) {
    __shared__ float tl[64][65];
    const int n0 = blockIdx.x * 64, k0 = blockIdx.y * 64;
    const int tid = threadIdx.x;
#pragma unroll
    for (int rep = 0; rep < 16; ++rep) {
        int idx = rep * 256 + tid;
        int r = idx >> 6, c = idx & 63;
        tl[r][c] = in[(size_t)(k0 + r) * N + n0 + c];
    }
    __syncthreads();
#pragma unroll
    for (int rep = 0; rep < 16; ++rep) {
        int idx = rep * 256 + tid;
        int r = idx >> 6, c = idx & 63;
        out[(size_t)(n0 + r) * K + k0 + c] = f2b(tl[c][r]);
    }
}

// ---------- GEMM1: qkv = x @ W_qkv + b, scatter to Q/K [B,H,T,D], V^T [B,H,D,T] ----------
__global__ __launch_bounds__(256) void gemm_qkv(const u16* __restrict__ xb,   // [4096][1024]
                                                const u16* __restrict__ wT,   // [3072][1024]
                                                const float* __restrict__ bias,
                                                u16* __restrict__ qg,
                                                u16* __restrict__ kg,
                                                u16* __restrict__ vtg) {
    __shared__ u16 As[64][40];
    __shared__ u16 Bs[64][40];
    const int m0 = blockIdx.y * 64, n0 = blockIdx.x * 64;
    const int tid = threadIdx.x;
    const int w = tid >> 6, lane = tid & 63;
    const int lr = lane & 15, lk = (lane >> 4) * 8;
    f32x4 acc[4] = {};
    const int srow = tid >> 2, scol = (tid & 3) * 8;
    for (int k0 = 0; k0 < 1024; k0 += 32) {
        __syncthreads();
        *reinterpret_cast<ushort8*>(&As[srow][scol]) =
            *reinterpret_cast<const ushort8*>(xb + (size_t)(m0 + srow) * 1024 + k0 + scol);
        *reinterpret_cast<ushort8*>(&Bs[srow][scol]) =
            *reinterpret_cast<const ushort8*>(wT + (size_t)(n0 + srow) * 1024 + k0 + scol);
        __syncthreads();
        bf16x8 a = *reinterpret_cast<const bf16x8*>(&As[w * 16 + lr][lk]);
#pragma unroll
        for (int ng = 0; ng < 4; ++ng) {
            bf16x8 b = *reinterpret_cast<const bf16x8*>(&Bs[ng * 16 + lr][lk]);
            acc[ng] = __builtin_amdgcn_mfma_f32_16x16x32_bf16(a, b, acc[ng], 0, 0, 0);
        }
    }
#pragma unroll
    for (int ng = 0; ng < 4; ++ng) {
#pragma unroll
        for (int reg = 0; reg < 4; ++reg) {
            int mg = m0 + w * 16 + (lane >> 4) * 4 + reg;
            int n = n0 + ng * 16 + lr;
            float val = acc[ng][reg] + bias[n];
            u16 u = f2b(val);
            int which = n >> 10, c = n & 1023;
            int h = c >> 6, dd = c & 63;
            int b = mg >> 11, t = mg & 2047;
            size_t bh = (size_t)(b * HH + h);
            if (which == 0)      qg[(bh * TB + t) * DD + dd] = u;
            else if (which == 1) kg[(bh * TB + t) * DD + dd] = u;
            else                 vtg[(bh * DD + dd) * TB + t] = u;
        }
    }
}

// ---------- flash attention: per (b,h, 64 q rows) ----------
__global__ __launch_bounds__(256) void attn(const u16* __restrict__ qg,
                                            const u16* __restrict__ kg,
                                            const u16* __restrict__ vtg,
                                            u16* __restrict__ ao) {
    __shared__ u16 Kt[64][72];      // [key][d]
    __shared__ u16 Vt[64][72];      // [d][key]
    __shared__ u16 Pl[4][16][72];   // per-wave P
    const int bh = blockIdx.y;       // 0..31
    const int q0 = blockIdx.x * 64;
    const int tid = threadIdx.x, w = tid >> 6, lane = tid & 63;
    const int lr = lane & 15, lk8 = (lane >> 4) * 8;
    const u16* qb = qg + (size_t)bh * TB * DD;
    const u16* kb = kg + (size_t)bh * TB * DD;
    const u16* vb = vtg + (size_t)bh * DD * TB;

    bf16x8 aq[2];
#pragma unroll
    for (int kk = 0; kk < 2; ++kk)
        aq[kk] = *reinterpret_cast<const bf16x8*>(qb + (size_t)(q0 + w * 16 + lr) * DD + kk * 32 + lk8);

    f32x4 o[4] = {};
    float mrow[4] = {-1e30f, -1e30f, -1e30f, -1e30f};
    float lrow[4] = {0.f, 0.f, 0.f, 0.f};

    for (int kt = 0; kt < 32; ++kt) {
        const int k0 = kt * 64;
        __syncthreads();
#pragma unroll
        for (int rep = 0; rep < 2; ++rep) {
            int c = rep * 256 + tid;        // 0..511
            int row = c >> 3, col = (c & 7) * 8;
            *reinterpret_cast<ushort8*>(&Kt[row][col]) =
                *reinterpret_cast<const ushort8*>(kb + (size_t)(k0 + row) * DD + col);
            *reinterpret_cast<ushort8*>(&Vt[row][col]) =
                *reinterpret_cast<const ushort8*>(vb + (size_t)row * TB + k0 + col);
        }
        __syncthreads();

        // S = Q K^T  (S[row][key]: row=(lane>>4)*4+reg, key=ng*16+lr)
        f32x4 s[4] = {};
#pragma unroll
        for (int kk = 0; kk < 2; ++kk) {
#pragma unroll
            for (int ng = 0; ng < 4; ++ng) {
                bf16x8 bk = *reinterpret_cast<const bf16x8*>(&Kt[ng * 16 + lr][kk * 32 + lk8]);
                s[ng] = __builtin_amdgcn_mfma_f32_16x16x32_bf16(aq[kk], bk, s[ng], 0, 0, 0);
            }
        }

        // online softmax
        float p[4][4], fr[4];
#pragma unroll
        for (int ng = 0; ng < 4; ++ng)
#pragma unroll
            for (int reg = 0; reg < 4; ++reg)
                p[ng][reg] = s[ng][reg] * 0.125f;
#pragma unroll
        for (int reg = 0; reg < 4; ++reg) {
            float v = fmaxf(fmaxf(p[0][reg], p[1][reg]), fmaxf(p[2][reg], p[3][reg]));
            v = fmaxf(v, __shfl_xor(v, 1));
            v = fmaxf(v, __shfl_xor(v, 2));
            v = fmaxf(v, __shfl_xor(v, 4));
            v = fmaxf(v, __shfl_xor(v, 8));
            float mn = fmaxf(mrow[reg], v);
            fr[reg] = __expf(mrow[reg] - mn);
            mrow[reg] = mn;
            float sum = 0.f;
#pragma unroll
            for (int ng = 0; ng < 4; ++ng) {
                p[ng][reg] = __expf(p[ng][reg] - mn);
                sum += p[ng][reg];
            }
            sum += __shfl_xor(sum, 1);
            sum += __shfl_xor(sum, 2);
            sum += __shfl_xor(sum, 4);
            sum += __shfl_xor(sum, 8);
            lrow[reg] = lrow[reg] * fr[reg] + sum;
        }
#pragma unroll
        for (int ng = 0; ng < 4; ++ng)
#pragma unroll
            for (int reg = 0; reg < 4; ++reg)
                o[ng][reg] *= fr[reg];

        // P -> per-wave LDS (re-fragment for PV)
#pragma unroll
        for (int reg = 0; reg < 4; ++reg) {
            int row = (lane >> 4) * 4 + reg;
#pragma unroll
            for (int ng = 0; ng < 4; ++ng)
                Pl[w][row][ng * 16 + lr] = f2b(p[ng][reg]);
        }

        // O += P V
#pragma unroll
        for (int kk = 0; kk < 2; ++kk) {
            bf16x8 ap = *reinterpret_cast<const bf16x8*>(&Pl[w][lr][kk * 32 + lk8]);
#pragma unroll
            for (int ng = 0; ng < 4; ++ng) {
                bf16x8 bv = *reinterpret_cast<const bf16x8*>(&Vt[ng * 16 + lr][kk * 32 + lk8]);
                o[ng] = __builtin_amdgcn_mfma_f32_16x16x32_bf16(ap, bv, o[ng], 0, 0, 0);
            }
        }
    }

    const int b = bh >> 4, h = bh & 15;
#pragma unroll
    for (int ng = 0; ng < 4; ++ng) {
#pragma unroll
        for (int reg = 0; reg < 4; ++reg) {
            int row = (lane >> 4) * 4 + reg;
            int t = q0 + w * 16 + row;
            int col = h * DD + ng * 16 + lr;
            ao[((size_t)(b * TB + t)) * CC + col] = f2b(o[ng][reg] / lrow[reg]);
        }
    }
}

// ---------- GEMM2: out = ao @ W_out + b_out (fp32 out) ----------
__global__ __launch_bounds__(256) void gemm_out(const u16* __restrict__ ao,   // [4096][1024]
                                                const u16* __restrict__ wT,   // [1024][1024]
                                                const float* __restrict__ bias,
                                                float* __restrict__ out) {
    __shared__ u16 As[64][40];
    __shared__ u16 Bs[64][40];
    const int m0 = blockIdx.y * 64, n0 = blockIdx.x * 64;
    const int tid = threadIdx.x;
    const int w = tid >> 6, lane = tid & 63;
    const int lr = lane & 15, lk = (lane >> 4) * 8;
    f32x4 acc[4] = {};
    const int srow = tid >> 2, scol = (tid & 3) * 8;
    for (int k0 = 0; k0 < 1024; k0 += 32) {
        __syncthreads();
        *reinterpret_cast<ushort8*>(&As[srow][scol]) =
            *reinterpret_cast<const ushort8*>(ao + (size_t)(m0 + srow) * 1024 + k0 + scol);
        *reinterpret_cast<ushort8*>(&Bs[srow][scol]) =
            *reinterpret_cast<const ushort8*>(wT + (size_t)(n0 + srow) * 1024 + k0 + scol);
        __syncthreads();
        bf16x8 a = *reinterpret_cast<const bf16x8*>(&As[w * 16 + lr][lk]);
#pragma unroll
        for (int ng = 0; ng < 4; ++ng) {
            bf16x8 b = *reinterpret_cast<const bf16x8*>(&Bs[ng * 16 + lr][lk]);
            acc[ng] = __builtin_amdgcn_mfma_f32_16x16x32_bf16(a, b, acc[ng], 0, 0, 0);
        }
    }
#pragma unroll
    for (int ng = 0; ng < 4; ++ng) {
#pragma unroll
        for (int reg = 0; reg < 4; ++reg) {
            int mg = m0 + w * 16 + (lane >> 4) * 4 + reg;
            int n = n0 + ng * 16 + lr;
            out[(size_t)mg * 1024 + n] = acc[ng][reg] + bias[n];
        }
    }
}

extern "C" void kernel_launch(void* const* d_in, const int* in_sizes, int n_in,
                              void* d_out, int out_size, void* d_ws, size_t ws_size,
                              hipStream_t stream) {
    const float* x     = (const float*)d_in[0];
    const float* W_qkv = (const float*)d_in[1];
    const float* b_qkv = (const float*)d_in[2];
    const float* W_out = (const float*)d_in[3];
    const float* b_out = (const float*)d_in[4];
    float* out = (float*)d_out;

    char* ws = (char*)d_ws;
    u16* xb    = (u16*)(ws);                       // 8 MB  x bf16 [4096][1024]
    u16* wqkvT = (u16*)(ws + (size_t)( 8u << 20)); // 6 MB  W_qkv^T bf16 [3072][1024]
    u16* woutT = (u16*)(ws + (size_t)(14u << 20)); // 2 MB  W_out^T bf16 [1024][1024]
    u16* qg    = (u16*)(ws + (size_t)(16u << 20)); // 8 MB  Q [B,H,T,D]
    u16* kg    = (u16*)(ws + (size_t)(24u << 20)); // 8 MB  K [B,H,T,D]
    u16* vtg   = (u16*)(ws + (size_t)(32u << 20)); // 8 MB  V^T [B,H,D,T]
    u16* ao    = xb;                               // reuse x buffer for attn-out

    hipLaunchKernelGGL(cvt_bf16, dim3(4096), dim3(256), 0, stream, x, xb, MM * CC);
    hipLaunchKernelGGL(transpose_cvt, dim3(48, 16), dim3(256), 0, stream, W_qkv, wqkvT, 1024, 3072);
    hipLaunchKernelGGL(transpose_cvt, dim3(16, 16), dim3(256), 0, stream, W_out, woutT, 1024, 1024);
    hipLaunchKernelGGL(gemm_qkv, dim3(48, 64), dim3(256), 0, stream, xb, wqkvT, b_qkv, qg, kg, vtg);
    hipLaunchKernelGGL(attn, dim3(32, 32), dim3(256), 0, stream, qg, kg, vtg, ao);
    hipLaunchKernelGGL(gemm_out, dim3(16, 64), dim3(256), 0, stream, ao, woutT, b_out, out);
}

// Round 2
// 162.713 us; speedup vs baseline: 1.4202x; 1.4202x over previous
//
#include <hip/hip_runtime.h>
#include <hip/hip_bf16.h>

// B=2, T=2048, C=1024, H=16, D=64
#define TB 2048
#define CC 1024
#define HH 16
#define DD 64
#define MM 4096     // B*T
#define N3 3072     // 3*C

typedef __bf16 bf16x8 __attribute__((ext_vector_type(8)));
typedef __bf16 bf16x4 __attribute__((ext_vector_type(4)));
typedef float f32x4 __attribute__((ext_vector_type(4)));
typedef unsigned short ushort8 __attribute__((ext_vector_type(8)));
typedef unsigned short u16;

// q pre-scale: 0.125 * log2(e)  (softmax done in exp2 domain)
#define QSCALE 0.180336880693612f

__device__ __forceinline__ u16 f2b(float f) {
    unsigned int x = __float_as_uint(f);
    x = (x + 0x7fffu + ((x >> 16) & 1u)) >> 16;
    return (u16)x;
}

__device__ __forceinline__ unsigned cvt_pk_bf16(float lo, float hi) {
    unsigned r;
    asm volatile("v_cvt_pk_bf16_f32 %0, %1, %2" : "=v"(r) : "v"(lo), "v"(hi));
    return r;
}

__device__ __forceinline__ void gld16(const u16* g, u16* l) {
    __builtin_amdgcn_global_load_lds(
        (const __attribute__((address_space(1))) unsigned int*)g,
        (__attribute__((address_space(3))) unsigned int*)l, 16, 0, 0);
}

// ---------- fp32 -> bf16 convert ----------
__global__ __launch_bounds__(256) void cvt_bf16(const float* __restrict__ in,
                                                u16* __restrict__ out, int n) {
    int i = (blockIdx.x * 256 + threadIdx.x) * 4;
    if (i >= n) return;
    float4 v = *reinterpret_cast<const float4*>(in + i);
    union { u16 u[4]; uint2 v2; } r;
    r.u[0] = f2b(v.x); r.u[1] = f2b(v.y); r.u[2] = f2b(v.z); r.u[3] = f2b(v.w);
    *reinterpret_cast<uint2*>(out + i) = r.v2;
}

// ---------- fp32 [K][N] -> bf16 [N][K] ----------
__global__ __launch_bounds__(256) void transpose_cvt(const float* __restrict__ in,
                                                     u16* __restrict__ out,
                                                     int K, int N) {
    __shared__ float tl[64][65];
    const int n0 = blockIdx.x * 64, k0 = blockIdx.y * 64;
    const int tid = threadIdx.x;
#pragma unroll
    for (int rep = 0; rep < 16; ++rep) {
        int idx = rep * 256 + tid;
        int r = idx >> 6, c = idx & 63;
        tl[r][c] = in[(size_t)(k0 + r) * N + n0 + c];
    }
    __syncthreads();
#pragma unroll
    for (int rep = 0; rep < 16; ++rep) {
        int idx = rep * 256 + tid;
        int r = idx >> 6, c = idx & 63;
        out[(size_t)(n0 + r) * K + k0 + c] = f2b(tl[c][r]);
    }
}

// ---------- GEMM1: 128x128 tile, BK=64, global_load_lds + XOR swizzle ----------
__global__ __launch_bounds__(256) void gemm_qkv(const u16* __restrict__ xb,   // [4096][1024]
                                                const u16* __restrict__ wT,   // [3072][1024]
                                                const float* __restrict__ bias,
                                                u16* __restrict__ qg,
                                                u16* __restrict__ kg,
                                                u16* __restrict__ vtg) {
    __shared__ u16 As[128 * 64];
    __shared__ u16 Bs[128 * 64];
    const int m0 = blockIdx.y * 128, n0 = blockIdx.x * 128;
    const int tid = threadIdx.x;
    const int w = tid >> 6, lane = tid & 63, lr = lane & 15, h = lane >> 4;
    const int wr = w >> 1, wc = w & 1;
    f32x4 acc[4][4] = {};

    for (int k0 = 0; k0 < 1024; k0 += 64) {
        __syncthreads();
#pragma unroll
        for (int j = 0; j < 4; ++j) {
            int L = j * 256 + tid;
            int r = L >> 3, c = L & 7;
            int csw = (c ^ (r & 7)) << 3;
            gld16(xb + (size_t)(m0 + r) * 1024 + k0 + csw, As + L * 8);
            gld16(wT + (size_t)(n0 + r) * 1024 + k0 + csw, Bs + L * 8);
        }
        __syncthreads();
#pragma unroll
        for (int kk = 0; kk < 2; ++kk) {
            bf16x8 a[4], b[4];
            int cc = kk * 4 + h;
#pragma unroll
            for (int m = 0; m < 4; ++m) {
                int R = wr * 64 + m * 16 + lr;
                a[m] = *reinterpret_cast<const bf16x8*>((const char*)As + R * 128 + ((cc ^ (R & 7)) << 4));
            }
#pragma unroll
            for (int n = 0; n < 4; ++n) {
                int R = wc * 64 + n * 16 + lr;
                b[n] = *reinterpret_cast<const bf16x8*>((const char*)Bs + R * 128 + ((cc ^ (R & 7)) << 4));
            }
#pragma unroll
            for (int m = 0; m < 4; ++m)
#pragma unroll
                for (int n = 0; n < 4; ++n)
                    acc[m][n] = __builtin_amdgcn_mfma_f32_16x16x32_bf16(a[m], b[n], acc[m][n], 0, 0, 0);
        }
    }

    const int nthird = n0 >> 10;    // uniform per block (128 | 1024)
#pragma unroll
    for (int n = 0; n < 4; ++n) {
        int ng = n0 + wc * 64 + n * 16 + lr;
        int c1 = ng & 1023;
        int hh = c1 >> 6, dd = c1 & 63;
        float bv = bias[ng];
#pragma unroll
        for (int m = 0; m < 4; ++m) {
#pragma unroll
            for (int reg = 0; reg < 4; ++reg) {
                int mg = m0 + wr * 64 + m * 16 + h * 4 + reg;
                int b = mg >> 11, t = mg & 2047;
                size_t bh = (size_t)b * HH + hh;
                float val = acc[m][n][reg] + bv;
                if (nthird == 0)      qg[(bh * TB + t) * DD + dd] = f2b(val * QSCALE);
                else if (nthird == 1) kg[(bh * TB + t) * DD + dd] = f2b(val);
                else                  vtg[(bh * DD + dd) * TB + t] = f2b(val);
            }
        }
    }
}

// ---------- flash attention: swapped QK^T, in-register softmax & P ----------
// Per block: 4 waves x 16 q-rows = 64 q-rows, KV tiles of 64.
// Lane (lr,h): after mfma(K,Q): s[ng][reg] = S[key=16ng+4h+reg][qrow=lr] (exp2 domain).
// PV uses permuted k-slots: slot(kk,h,j) -> key 32kk+16(j>>2)+4h+(j&3), so the
// A-fragment is the lane's own P values; V read with the same permutation.
__global__ __launch_bounds__(256) void attn(const u16* __restrict__ qg,
                                            const u16* __restrict__ kg,
                                            const u16* __restrict__ vtg,
                                            u16* __restrict__ ao) {
    __shared__ u16 Kt[64 * 64];
    __shared__ u16 Vt[64 * 64];
    const int bh = blockIdx.y;
    const int q0 = blockIdx.x * 64;
    const int tid = threadIdx.x, w = tid >> 6, lane = tid & 63;
    const int lr = lane & 15, h = lane >> 4;
    const u16* qb = qg + (size_t)bh * TB * DD;
    const u16* kb = kg + (size_t)bh * TB * DD;
    const u16* vb = vtg + (size_t)bh * DD * TB;

    bf16x8 bq[2];
#pragma unroll
    for (int kk = 0; kk < 2; ++kk)
        bq[kk] = *reinterpret_cast<const bf16x8*>(qb + (size_t)(q0 + w * 16 + lr) * DD + kk * 32 + h * 8);

    f32x4 o[4] = {};          // o[ngd][reg] = O[qrow=h*4+reg][d=ngd*16+lr]
    float m_r = -1e30f;       // running max for qrow=lr (replicated across h)
    float l_r = 0.f;

    for (int kt = 0; kt < 32; ++kt) {
        const int k0 = kt * 64;
        __syncthreads();
#pragma unroll
        for (int j = 0; j < 2; ++j) {
            int L = j * 256 + tid;
            int r = L >> 3, c = L & 7;
            int csw = (c ^ (r & 7)) << 3;
            gld16(kb + (size_t)(k0 + r) * DD + csw, Kt + L * 8);
            gld16(vb + (size_t)r * TB + k0 + csw, Vt + L * 8);
        }
        __syncthreads();

        // S^T = K Q^T
        f32x4 s[4] = {};
#pragma unroll
        for (int kk = 0; kk < 2; ++kk) {
            int cc = kk * 4 + h;
#pragma unroll
            for (int ng = 0; ng < 4; ++ng) {
                int R = ng * 16 + lr;
                bf16x8 ak = *reinterpret_cast<const bf16x8*>((const char*)Kt + R * 128 + ((cc ^ (R & 7)) << 4));
                s[ng] = __builtin_amdgcn_mfma_f32_16x16x32_bf16(ak, bq[kk], s[ng], 0, 0, 0);
            }
        }

        // online softmax (exp2 domain), defer-max
        float pm = s[0][0];
#pragma unroll
        for (int ng = 0; ng < 4; ++ng)
#pragma unroll
            for (int reg = 0; reg < 4; ++reg)
                pm = fmaxf(pm, s[ng][reg]);
        pm = fmaxf(pm, __shfl_xor(pm, 16));
        pm = fmaxf(pm, __shfl_xor(pm, 32));

        if (!__all(pm - m_r <= 8.0f)) {
            float mn = fmaxf(m_r, pm);
            float fr = __builtin_amdgcn_exp2f(m_r - mn);
            m_r = mn;
            l_r *= fr;
#pragma unroll
            for (int reg = 0; reg < 4; ++reg) {
                float fro = __shfl(fr, h * 4 + reg);
#pragma unroll
                for (int ngd = 0; ngd < 4; ++ngd)
                    o[ngd][reg] *= fro;
            }
        }

        float p[4][4];
        float sum = 0.f;
#pragma unroll
        for (int ng = 0; ng < 4; ++ng)
#pragma unroll
            for (int reg = 0; reg < 4; ++reg) {
                p[ng][reg] = __builtin_amdgcn_exp2f(s[ng][reg] - m_r);
                sum += p[ng][reg];
            }
        sum += __shfl_xor(sum, 16);
        sum += __shfl_xor(sum, 32);
        l_r += sum;

        unsigned pk[4][2];
#pragma unroll
        for (int ng = 0; ng < 4; ++ng) {
            pk[ng][0] = cvt_pk_bf16(p[ng][0], p[ng][1]);
            pk[ng][1] = cvt_pk_bf16(p[ng][2], p[ng][3]);
        }

        // O += P V with permuted k-slots
#pragma unroll
        for (int kk = 0; kk < 2; ++kk) {
            union { unsigned u[4]; bf16x8 v; } ap;
            ap.u[0] = pk[2 * kk][0];     ap.u[1] = pk[2 * kk][1];
            ap.u[2] = pk[2 * kk + 1][0]; ap.u[3] = pk[2 * kk + 1][1];
            int ca = 4 * kk + (h >> 1);
            int cb = ca + 2;
            int woff = 8 * (h & 1);
#pragma unroll
            for (int ngd = 0; ngd < 4; ++ngd) {
                int d = ngd * 16 + lr;
                const char* vrow = (const char*)Vt + d * 128;
                bf16x4 v0 = *reinterpret_cast<const bf16x4*>(vrow + ((ca ^ (d & 7)) << 4) + woff);
                bf16x4 v1 = *reinterpret_cast<const bf16x4*>(vrow + ((cb ^ (d & 7)) << 4) + woff);
                bf16x8 bv = __builtin_shufflevector(v0, v1, 0, 1, 2, 3, 4, 5, 6, 7);
                o[ngd] = __builtin_amdgcn_mfma_f32_16x16x32_bf16(ap.v, bv, o[ngd], 0, 0, 0);
            }
        }
    }

    float linv[4];
#pragma unroll
    for (int reg = 0; reg < 4; ++reg)
        linv[reg] = 1.0f / __shfl(l_r, h * 4 + reg);

    const int b = bh >> 4, hh = bh & 15;
#pragma unroll
    for (int ngd = 0; ngd < 4; ++ngd) {
#pragma unroll
        for (int reg = 0; reg < 4; ++reg) {
            int t = q0 + w * 16 + h * 4 + reg;
            int col = hh * DD + ngd * 16 + lr;
            ao[((size_t)(b * TB + t)) * CC + col] = f2b(o[ngd][reg] * linv[reg]);
        }
    }
}

// ---------- GEMM2: out = ao @ W_out + b_out ----------
__global__ __launch_bounds__(256) void gemm_out(const u16* __restrict__ ao,   // [4096][1024]
                                                const u16* __restrict__ wT,   // [1024][1024]
                                                const float* __restrict__ bias,
                                                float* __restrict__ out) {
    __shared__ u16 As[128 * 64];
    __shared__ u16 Bs[128 * 64];
    const int m0 = blockIdx.y * 128, n0 = blockIdx.x * 128;
    const int tid = threadIdx.x;
    const int w = tid >> 6, lane = tid & 63, lr = lane & 15, h = lane >> 4;
    const int wr = w >> 1, wc = w & 1;
    f32x4 acc[4][4] = {};

    for (int k0 = 0; k0 < 1024; k0 += 64) {
        __syncthreads();
#pragma unroll
        for (int j = 0; j < 4; ++j) {
            int L = j * 256 + tid;
            int r = L >> 3, c = L & 7;
            int csw = (c ^ (r & 7)) << 3;
            gld16(ao + (size_t)(m0 + r) * 1024 + k0 + csw, As + L * 8);
            gld16(wT + (size_t)(n0 + r) * 1024 + k0 + csw, Bs + L * 8);
        }
        __syncthreads();
#pragma unroll
        for (int kk = 0; kk < 2; ++kk) {
            bf16x8 a[4], b[4];
            int cc = kk * 4 + h;
#pragma unroll
            for (int m = 0; m < 4; ++m) {
                int R = wr * 64 + m * 16 + lr;
                a[m] = *reinterpret_cast<const bf16x8*>((const char*)As + R * 128 + ((cc ^ (R & 7)) << 4));
            }
#pragma unroll
            for (int n = 0; n < 4; ++n) {
                int R = wc * 64 + n * 16 + lr;
                b[n] = *reinterpret_cast<const bf16x8*>((const char*)Bs + R * 128 + ((cc ^ (R & 7)) << 4));
            }
#pragma unroll
            for (int m = 0; m < 4; ++m)
#pragma unroll
                for (int n = 0; n < 4; ++n)
                    acc[m][n] = __builtin_amdgcn_mfma_f32_16x16x32_bf16(a[m], b[n], acc[m][n], 0, 0, 0);
        }
    }

#pragma unroll
    for (int n = 0; n < 4; ++n) {
        int ng = n0 + wc * 64 + n * 16 + lr;
        float bv = bias[ng];
#pragma unroll
        for (int m = 0; m < 4; ++m) {
#pragma unroll
            for (int reg = 0; reg < 4; ++reg) {
                int mg = m0 + wr * 64 + m * 16 + h * 4 + reg;
                out[(size_t)mg * 1024 + ng] = acc[m][n][reg] + bv;
            }
        }
    }
}

extern "C" void kernel_launch(void* const* d_in, const int* in_sizes, int n_in,
                              void* d_out, int out_size, void* d_ws, size_t ws_size,
                              hipStream_t stream) {
    const float* x     = (const float*)d_in[0];
    const float* W_qkv = (const float*)d_in[1];
    const float* b_qkv = (const float*)d_in[2];
    const float* W_out = (const float*)d_in[3];
    const float* b_out = (const float*)d_in[4];
    float* out = (float*)d_out;

    char* ws = (char*)d_ws;
    u16* xb    = (u16*)(ws);                       // 8 MB  x bf16 [4096][1024]
    u16* wqkvT = (u16*)(ws + (size_t)( 8u << 20)); // 6 MB  W_qkv^T bf16 [3072][1024]
    u16* woutT = (u16*)(ws + (size_t)(14u << 20)); // 2 MB  W_out^T bf16 [1024][1024]
    u16* qg    = (u16*)(ws + (size_t)(16u << 20)); // 8 MB  Q [B,H,T,D] (pre-scaled)
    u16* kg    = (u16*)(ws + (size_t)(24u << 20)); // 8 MB  K [B,H,T,D]
    u16* vtg   = (u16*)(ws + (size_t)(32u << 20)); // 8 MB  V^T [B,H,D,T]
    u16* ao    = xb;                               // reuse x buffer for attn-out

    hipLaunchKernelGGL(cvt_bf16, dim3(4096), dim3(256), 0, stream, x, xb, MM * CC);
    hipLaunchKernelGGL(transpose_cvt, dim3(48, 16), dim3(256), 0, stream, W_qkv, wqkvT, 1024, 3072);
    hipLaunchKernelGGL(transpose_cvt, dim3(16, 16), dim3(256), 0, stream, W_out, woutT, 1024, 1024);
    hipLaunchKernelGGL(gemm_qkv, dim3(24, 32), dim3(256), 0, stream, xb, wqkvT, b_qkv, qg, kg, vtg);
    hipLaunchKernelGGL(attn, dim3(32, 32), dim3(256), 0, stream, qg, kg, vtg, ao);
    hipLaunchKernelGGL(gemm_out, dim3(8, 32), dim3(256), 0, stream, ao, woutT, b_out, out);
}

// Round 3
// 149.025 us; speedup vs baseline: 1.5506x; 1.0919x over previous
//
#include <hip/hip_runtime.h>
#include <hip/hip_bf16.h>

// B=2, T=2048, C=1024, H=16, D=64
#define TB 2048
#define CC 1024
#define HH 16
#define DD 64
#define MM 4096     // B*T
#define N3 3072     // 3*C

typedef __bf16 bf16x8 __attribute__((ext_vector_type(8)));
typedef __bf16 bf16x4 __attribute__((ext_vector_type(4)));
typedef float f32x4 __attribute__((ext_vector_type(4)));
typedef unsigned short ushort8 __attribute__((ext_vector_type(8)));
typedef unsigned short u16;

// q pre-scale: 0.125 * log2(e)  (softmax done in exp2 domain)
#define QSCALE 0.180336880693612f

__device__ __forceinline__ u16 f2b(float f) {
    unsigned int x = __float_as_uint(f);
    x = (x + 0x7fffu + ((x >> 16) & 1u)) >> 16;
    return (u16)x;
}

__device__ __forceinline__ unsigned cvt_pk_bf16(float lo, float hi) {
    unsigned r;
    asm volatile("v_cvt_pk_bf16_f32 %0, %1, %2" : "=v"(r) : "v"(lo), "v"(hi));
    return r;
}

__device__ __forceinline__ void gld16(const u16* g, u16* l) {
    __builtin_amdgcn_global_load_lds(
        (const __attribute__((address_space(1))) unsigned int*)g,
        (__attribute__((address_space(3))) unsigned int*)l, 16, 0, 0);
}

// ---------- fp32 -> bf16 convert ----------
__global__ __launch_bounds__(256) void cvt_bf16(const float* __restrict__ in,
                                                u16* __restrict__ out, int n) {
    int i = (blockIdx.x * 256 + threadIdx.x) * 4;
    if (i >= n) return;
    float4 v = *reinterpret_cast<const float4*>(in + i);
    union { u16 u[4]; uint2 v2; } r;
    r.u[0] = f2b(v.x); r.u[1] = f2b(v.y); r.u[2] = f2b(v.z); r.u[3] = f2b(v.w);
    *reinterpret_cast<uint2*>(out + i) = r.v2;
}

// ---------- fp32 [K][N] -> bf16 [N][K], both weights in one launch ----------
__global__ __launch_bounds__(256) void transpose_cvt2(const float* __restrict__ wqkv,
                                                      u16* __restrict__ wqkvT,
                                                      const float* __restrict__ wout,
                                                      u16* __restrict__ woutT) {
    __shared__ float tl[64][65];
    const int bx = blockIdx.x;
    const float* in; u16* out; int N, n0;
    if (bx < 48) { in = wqkv; out = wqkvT; N = 3072; n0 = bx * 64; }
    else         { in = wout; out = woutT; N = 1024; n0 = (bx - 48) * 64; }
    const int k0 = blockIdx.y * 64;
    const int tid = threadIdx.x;
#pragma unroll
    for (int rep = 0; rep < 16; ++rep) {
        int idx = rep * 256 + tid;
        int r = idx >> 6, c = idx & 63;
        tl[r][c] = in[(size_t)(k0 + r) * N + n0 + c];
    }
    __syncthreads();
#pragma unroll
    for (int rep = 0; rep < 16; ++rep) {
        int idx = rep * 256 + tid;
        int r = idx >> 6, c = idx & 63;
        out[(size_t)(n0 + r) * 1024 + k0 + c] = f2b(tl[c][r]);
    }
}

// ---------- GEMM1: 128x128 tile, BK=64, global_load_lds + XOR swizzle ----------
__global__ __launch_bounds__(256) void gemm_qkv(const u16* __restrict__ xb,   // [4096][1024]
                                                const u16* __restrict__ wT,   // [3072][1024]
                                                const float* __restrict__ bias,
                                                u16* __restrict__ qg,
                                                u16* __restrict__ kg,
                                                u16* __restrict__ vtg) {
    __shared__ u16 smem[2 * 128 * 64];           // As | Bs ; reused as [128][128] for V^T
    u16* As = smem;
    u16* Bs = smem + 128 * 64;
    const int m0 = blockIdx.y * 128, n0 = blockIdx.x * 128;
    const int tid = threadIdx.x;
    const int w = tid >> 6, lane = tid & 63, lr = lane & 15, h = lane >> 4;
    const int wr = w >> 1, wc = w & 1;
    f32x4 acc[4][4] = {};

    for (int k0 = 0; k0 < 1024; k0 += 64) {
        __syncthreads();
#pragma unroll
        for (int j = 0; j < 4; ++j) {
            int L = j * 256 + tid;
            int r = L >> 3, c = L & 7;
            int csw = (c ^ (r & 7)) << 3;
            gld16(xb + (size_t)(m0 + r) * 1024 + k0 + csw, As + L * 8);
            gld16(wT + (size_t)(n0 + r) * 1024 + k0 + csw, Bs + L * 8);
        }
        __syncthreads();
#pragma unroll
        for (int kk = 0; kk < 2; ++kk) {
            bf16x8 a[4], b[4];
            int cc = kk * 4 + h;
#pragma unroll
            for (int m = 0; m < 4; ++m) {
                int R = wr * 64 + m * 16 + lr;
                a[m] = *reinterpret_cast<const bf16x8*>((const char*)As + R * 128 + ((cc ^ (R & 7)) << 4));
            }
#pragma unroll
            for (int n = 0; n < 4; ++n) {
                int R = wc * 64 + n * 16 + lr;
                b[n] = *reinterpret_cast<const bf16x8*>((const char*)Bs + R * 128 + ((cc ^ (R & 7)) << 4));
            }
#pragma unroll
            for (int m = 0; m < 4; ++m)
#pragma unroll
                for (int n = 0; n < 4; ++n)
                    acc[m][n] = __builtin_amdgcn_mfma_f32_16x16x32_bf16(a[m], b[n], acc[m][n], 0, 0, 0);
        }
    }

    const int nthird = n0 >> 10;    // uniform per block (128 | 1024)
    if (nthird == 2) {
        // ---- V: transpose 128x128 subtile through LDS, coalesced V^T stores ----
        __syncthreads();
#pragma unroll
        for (int n = 0; n < 4; ++n) {
            int nloc = wc * 64 + n * 16 + lr;
            unsigned xorv = (unsigned)(nloc & 15) << 4;
            float bv = bias[n0 + nloc];
#pragma unroll
            for (int m = 0; m < 4; ++m) {
                int mloc = wr * 64 + m * 16 + h * 4;
                union { u16 u[4]; unsigned long long ll; } pk4;
#pragma unroll
                for (int reg = 0; reg < 4; ++reg)
                    pk4.u[reg] = f2b(acc[m][n][reg] + bv);
                *reinterpret_cast<unsigned long long*>(
                    (char*)smem + nloc * 256 + ((unsigned)(mloc * 2) ^ xorv)) = pk4.ll;
            }
        }
        __syncthreads();
        const int b = m0 >> 11, t0 = m0 & 2047;
        const int c16 = tid & 15;
#pragma unroll
        for (int step = 0; step < 8; ++step) {
            int row = (tid >> 4) + step * 16;           // nloc 0..127
            ushort8 vch = *reinterpret_cast<const ushort8*>(
                (const char*)smem + row * 256 + ((unsigned)((c16 ^ (row & 15)) << 4)));
            int c1 = (n0 + row) & 1023;
            int hh = c1 >> 6, dd = c1 & 63;
            *reinterpret_cast<ushort8*>(
                vtg + ((size_t)(b * HH + hh) * DD + dd) * TB + t0 + c16 * 8) = vch;
        }
    } else {
#pragma unroll
        for (int n = 0; n < 4; ++n) {
            int ng = n0 + wc * 64 + n * 16 + lr;
            int c1 = ng & 1023;
            int hh = c1 >> 6, dd = c1 & 63;
            float bv = bias[ng];
#pragma unroll
            for (int m = 0; m < 4; ++m) {
#pragma unroll
                for (int reg = 0; reg < 4; ++reg) {
                    int mg = m0 + wr * 64 + m * 16 + h * 4 + reg;
                    int b = mg >> 11, t = mg & 2047;
                    size_t bh = (size_t)b * HH + hh;
                    float val = acc[m][n][reg] + bv;
                    if (nthird == 0) qg[(bh * TB + t) * DD + dd] = f2b(val * QSCALE);
                    else             kg[(bh * TB + t) * DD + dd] = f2b(val);
                }
            }
        }
    }
}

// ---------- flash attention: swapped QK^T, in-register softmax & P, dbuf K/V ----------
__global__ __launch_bounds__(256) void attn(const u16* __restrict__ qg,
                                            const u16* __restrict__ kg,
                                            const u16* __restrict__ vtg,
                                            u16* __restrict__ ao) {
    __shared__ u16 Kt[2][64 * 64];
    __shared__ u16 Vt[2][64 * 64];
    const int bh = blockIdx.y;
    const int q0 = blockIdx.x * 64;
    const int tid = threadIdx.x, w = tid >> 6, lane = tid & 63;
    const int lr = lane & 15, h = lane >> 4;
    const u16* qb = qg + (size_t)bh * TB * DD;
    const u16* kb = kg + (size_t)bh * TB * DD;
    const u16* vb = vtg + (size_t)bh * DD * TB;

#define STAGE(buf, kbase) do {                                                   \
    _Pragma("unroll")                                                            \
    for (int j = 0; j < 2; ++j) {                                                \
        int L = j * 256 + tid;                                                   \
        int r = L >> 3, c = L & 7;                                               \
        int csw = (c ^ (r & 7)) << 3;                                            \
        gld16(kb + (size_t)((kbase) + r) * DD + csw, Kt[buf] + L * 8);           \
        gld16(vb + (size_t)r * TB + (kbase) + csw, Vt[buf] + L * 8);             \
    } } while (0)

    bf16x8 bq[2];
#pragma unroll
    for (int kk = 0; kk < 2; ++kk)
        bq[kk] = *reinterpret_cast<const bf16x8*>(qb + (size_t)(q0 + w * 16 + lr) * DD + kk * 32 + h * 8);

    f32x4 o[4] = {};          // o[ngd][reg] = O[qrow=h*4+reg][d=ngd*16+lr]
    float m_r = -1e30f;       // running max for qrow=lr (replicated across h)
    float l_r = 0.f;

    STAGE(0, 0);
    __syncthreads();
    int cur = 0;

    for (int kt = 0; kt < 32; ++kt) {
        if (kt < 31) STAGE(cur ^ 1, (kt + 1) * 64);
        const u16* ktc = Kt[cur];
        const u16* vtc = Vt[cur];

        // S^T = K Q^T
        f32x4 s[4] = {};
#pragma unroll
        for (int kk = 0; kk < 2; ++kk) {
            int cc = kk * 4 + h;
#pragma unroll
            for (int ng = 0; ng < 4; ++ng) {
                int R = ng * 16 + lr;
                bf16x8 ak = *reinterpret_cast<const bf16x8*>((const char*)ktc + R * 128 + ((cc ^ (R & 7)) << 4));
                s[ng] = __builtin_amdgcn_mfma_f32_16x16x32_bf16(ak, bq[kk], s[ng], 0, 0, 0);
            }
        }

        // online softmax (exp2 domain), defer-max; max3-friendly reduce
        float t0 = fmaxf(fmaxf(s[0][0], s[0][1]), s[0][2]);
        float t1 = fmaxf(fmaxf(s[0][3], s[1][0]), s[1][1]);
        float t2 = fmaxf(fmaxf(s[1][2], s[1][3]), s[2][0]);
        float t3 = fmaxf(fmaxf(s[2][1], s[2][2]), s[2][3]);
        float t4 = fmaxf(fmaxf(s[3][0], s[3][1]), s[3][2]);
        float pm = fmaxf(fmaxf(fmaxf(t0, t1), fmaxf(t2, t3)), fmaxf(t4, s[3][3]));
        pm = fmaxf(pm, __shfl_xor(pm, 16));
        pm = fmaxf(pm, __shfl_xor(pm, 32));

        if (!__all(pm - m_r <= 8.0f)) {
            float mn = fmaxf(m_r, pm);
            float fr = __builtin_amdgcn_exp2f(m_r - mn);
            m_r = mn;
            l_r *= fr;
#pragma unroll
            for (int reg = 0; reg < 4; ++reg) {
                float fro = __shfl(fr, h * 4 + reg);
#pragma unroll
                for (int ngd = 0; ngd < 4; ++ngd)
                    o[ngd][reg] *= fro;
            }
        }

        float p[4][4];
        float sum = 0.f;
#pragma unroll
        for (int ng = 0; ng < 4; ++ng)
#pragma unroll
            for (int reg = 0; reg < 4; ++reg) {
                p[ng][reg] = __builtin_amdgcn_exp2f(s[ng][reg] - m_r);
                sum += p[ng][reg];
            }
        sum += __shfl_xor(sum, 16);
        sum += __shfl_xor(sum, 32);
        l_r += sum;

        unsigned pk[4][2];
#pragma unroll
        for (int ng = 0; ng < 4; ++ng) {
            pk[ng][0] = cvt_pk_bf16(p[ng][0], p[ng][1]);
            pk[ng][1] = cvt_pk_bf16(p[ng][2], p[ng][3]);
        }

        // O += P V with permuted k-slots
#pragma unroll
        for (int kk = 0; kk < 2; ++kk) {
            union { unsigned u[4]; bf16x8 v; } ap;
            ap.u[0] = pk[2 * kk][0];     ap.u[1] = pk[2 * kk][1];
            ap.u[2] = pk[2 * kk + 1][0]; ap.u[3] = pk[2 * kk + 1][1];
            int ca = 4 * kk + (h >> 1);
            int cb = ca + 2;
            int woff = 8 * (h & 1);
#pragma unroll
            for (int ngd = 0; ngd < 4; ++ngd) {
                int d = ngd * 16 + lr;
                const char* vrow = (const char*)vtc + d * 128;
                bf16x4 v0 = *reinterpret_cast<const bf16x4*>(vrow + ((ca ^ (d & 7)) << 4) + woff);
                bf16x4 v1 = *reinterpret_cast<const bf16x4*>(vrow + ((cb ^ (d & 7)) << 4) + woff);
                bf16x8 bv = __builtin_shufflevector(v0, v1, 0, 1, 2, 3, 4, 5, 6, 7);
                o[ngd] = __builtin_amdgcn_mfma_f32_16x16x32_bf16(ap.v, bv, o[ngd], 0, 0, 0);
            }
        }
        __syncthreads();
        cur ^= 1;
    }
#undef STAGE

    float linv[4];
#pragma unroll
    for (int reg = 0; reg < 4; ++reg)
        linv[reg] = 1.0f / __shfl(l_r, h * 4 + reg);

    const int b = bh >> 4, hh = bh & 15;
#pragma unroll
    for (int ngd = 0; ngd < 4; ++ngd) {
#pragma unroll
        for (int reg = 0; reg < 4; ++reg) {
            int t = q0 + w * 16 + h * 4 + reg;
            int col = hh * DD + ngd * 16 + lr;
            ao[((size_t)(b * TB + t)) * CC + col] = f2b(o[ngd][reg] * linv[reg]);
        }
    }
}

// ---------- GEMM2: out = ao @ W_out + b_out ----------
__global__ __launch_bounds__(256) void gemm_out(const u16* __restrict__ ao,   // [4096][1024]
                                                const u16* __restrict__ wT,   // [1024][1024]
                                                const float* __restrict__ bias,
                                                float* __restrict__ out) {
    __shared__ u16 As[128 * 64];
    __shared__ u16 Bs[128 * 64];
    const int m0 = blockIdx.y * 128, n0 = blockIdx.x * 128;
    const int tid = threadIdx.x;
    const int w = tid >> 6, lane = tid & 63, lr = lane & 15, h = lane >> 4;
    const int wr = w >> 1, wc = w & 1;
    f32x4 acc[4][4] = {};

    for (int k0 = 0; k0 < 1024; k0 += 64) {
        __syncthreads();
#pragma unroll
        for (int j = 0; j < 4; ++j) {
            int L = j * 256 + tid;
            int r = L >> 3, c = L & 7;
            int csw = (c ^ (r & 7)) << 3;
            gld16(ao + (size_t)(m0 + r) * 1024 + k0 + csw, As + L * 8);
            gld16(wT + (size_t)(n0 + r) * 1024 + k0 + csw, Bs + L * 8);
        }
        __syncthreads();
#pragma unroll
        for (int kk = 0; kk < 2; ++kk) {
            bf16x8 a[4], b[4];
            int cc = kk * 4 + h;
#pragma unroll
            for (int m = 0; m < 4; ++m) {
                int R = wr * 64 + m * 16 + lr;
                a[m] = *reinterpret_cast<const bf16x8*>((const char*)As + R * 128 + ((cc ^ (R & 7)) << 4));
            }
#pragma unroll
            for (int n = 0; n < 4; ++n) {
                int R = wc * 64 + n * 16 + lr;
                b[n] = *reinterpret_cast<const bf16x8*>((const char*)Bs + R * 128 + ((cc ^ (R & 7)) << 4));
            }
#pragma unroll
            for (int m = 0; m < 4; ++m)
#pragma unroll
                for (int n = 0; n < 4; ++n)
                    acc[m][n] = __builtin_amdgcn_mfma_f32_16x16x32_bf16(a[m], b[n], acc[m][n], 0, 0, 0);
        }
    }

#pragma unroll
    for (int n = 0; n < 4; ++n) {
        int ng = n0 + wc * 64 + n * 16 + lr;
        float bv = bias[ng];
#pragma unroll
        for (int m = 0; m < 4; ++m) {
#pragma unroll
            for (int reg = 0; reg < 4; ++reg) {
                int mg = m0 + wr * 64 + m * 16 + h * 4 + reg;
                out[(size_t)mg * 1024 + ng] = acc[m][n][reg] + bv;
            }
        }
    }
}

extern "C" void kernel_launch(void* const* d_in, const int* in_sizes, int n_in,
                              void* d_out, int out_size, void* d_ws, size_t ws_size,
                              hipStream_t stream) {
    const float* x     = (const float*)d_in[0];
    const float* W_qkv = (const float*)d_in[1];
    const float* b_qkv = (const float*)d_in[2];
    const float* W_out = (const float*)d_in[3];
    const float* b_out = (const float*)d_in[4];
    float* out = (float*)d_out;

    char* ws = (char*)d_ws;
    u16* xb    = (u16*)(ws);                       // 8 MB  x bf16 [4096][1024]
    u16* wqkvT = (u16*)(ws + (size_t)( 8u << 20)); // 6 MB  W_qkv^T bf16 [3072][1024]
    u16* woutT = (u16*)(ws + (size_t)(14u << 20)); // 2 MB  W_out^T bf16 [1024][1024]
    u16* qg    = (u16*)(ws + (size_t)(16u << 20)); // 8 MB  Q [B,H,T,D] (pre-scaled)
    u16* kg    = (u16*)(ws + (size_t)(24u << 20)); // 8 MB  K [B,H,T,D]
    u16* vtg   = (u16*)(ws + (size_t)(32u << 20)); // 8 MB  V^T [B,H,D,T]
    u16* ao    = xb;                               // reuse x buffer for attn-out

    hipLaunchKernelGGL(cvt_bf16, dim3(4096), dim3(256), 0, stream, x, xb, MM * CC);
    hipLaunchKernelGGL(transpose_cvt2, dim3(64, 16), dim3(256), 0, stream, W_qkv, wqkvT, W_out, woutT);
    hipLaunchKernelGGL(gemm_qkv, dim3(24, 32), dim3(256), 0, stream, xb, wqkvT, b_qkv, qg, kg, vtg);
    hipLaunchKernelGGL(attn, dim3(32, 32), dim3(256), 0, stream, qg, kg, vtg, ao);
    hipLaunchKernelGGL(gemm_out, dim3(8, 32), dim3(256), 0, stream, ao, woutT, b_out, out);
}

// Round 4
// 123.992 us; speedup vs baseline: 1.8637x; 1.2019x over previous
//
#include <hip/hip_runtime.h>
#include <hip/hip_bf16.h>

// B=2, T=2048, C=1024, H=16, D=64
#define TB 2048
#define CC 1024
#define HH 16
#define DD 64
#define MM 4096     // B*T
#define N3 3072     // 3*C
#define KVB 128
#define NT (TB / KVB)   // 16

typedef __bf16 bf16x8 __attribute__((ext_vector_type(8)));
typedef float f32x4 __attribute__((ext_vector_type(4)));
typedef unsigned short ushort8 __attribute__((ext_vector_type(8)));
typedef unsigned short u16;

// q pre-scale: 0.125 * log2(e)  (softmax done in exp2 domain)
#define QSCALE 0.180336880693612f

__device__ __forceinline__ u16 f2b(float f) {
    unsigned int x = __float_as_uint(f);
    x = (x + 0x7fffu + ((x >> 16) & 1u)) >> 16;
    return (u16)x;
}

__device__ __forceinline__ unsigned cvt_pk_bf16(float lo, float hi) {
    unsigned r;
    asm volatile("v_cvt_pk_bf16_f32 %0, %1, %2" : "=v"(r) : "v"(lo), "v"(hi));
    return r;
}

__device__ __forceinline__ void gld16(const u16* g, u16* l) {
    __builtin_amdgcn_global_load_lds(
        (const __attribute__((address_space(1))) unsigned int*)g,
        (__attribute__((address_space(3))) unsigned int*)l, 16, 0, 0);
}

// ---------- fp32 -> bf16 convert ----------
__global__ __launch_bounds__(256) void cvt_bf16(const float* __restrict__ in,
                                                u16* __restrict__ out, int n) {
    int i = (blockIdx.x * 256 + threadIdx.x) * 4;
    if (i >= n) return;
    float4 v = *reinterpret_cast<const float4*>(in + i);
    union { u16 u[4]; uint2 v2; } r;
    r.u[0] = f2b(v.x); r.u[1] = f2b(v.y); r.u[2] = f2b(v.z); r.u[3] = f2b(v.w);
    *reinterpret_cast<uint2*>(out + i) = r.v2;
}

// ---------- fp32 [K][N] -> bf16 [N][K], both weights in one launch ----------
__global__ __launch_bounds__(256) void transpose_cvt2(const float* __restrict__ wqkv,
                                                      u16* __restrict__ wqkvT,
                                                      const float* __restrict__ wout,
                                                      u16* __restrict__ woutT) {
    __shared__ float tl[64][65];
    const int bx = blockIdx.x;
    const float* in; u16* out; int N, n0;
    if (bx < 48) { in = wqkv; out = wqkvT; N = 3072; n0 = bx * 64; }
    else         { in = wout; out = woutT; N = 1024; n0 = (bx - 48) * 64; }
    const int k0 = blockIdx.y * 64;
    const int tid = threadIdx.x;
#pragma unroll
    for (int rep = 0; rep < 16; ++rep) {
        int idx = rep * 256 + tid;
        int r = idx >> 6, c = idx & 63;
        tl[r][c] = in[(size_t)(k0 + r) * N + n0 + c];
    }
    __syncthreads();
#pragma unroll
    for (int rep = 0; rep < 16; ++rep) {
        int idx = rep * 256 + tid;
        int r = idx >> 6, c = idx & 63;
        out[(size_t)(n0 + r) * 1024 + k0 + c] = f2b(tl[c][r]);
    }
}

// ---------- GEMM1: 128x128 tile, BK=64, global_load_lds + XOR swizzle ----------
// V third is written key-PERMUTED: within each 32-token block, token offset
// o = 16a+4h+r is stored at position 8h+4a+r (matches attn's PV A-fragment).
__global__ __launch_bounds__(256) void gemm_qkv(const u16* __restrict__ xb,   // [4096][1024]
                                                const u16* __restrict__ wT,   // [3072][1024]
                                                const float* __restrict__ bias,
                                                u16* __restrict__ qg,
                                                u16* __restrict__ kg,
                                                u16* __restrict__ vtg) {
    __shared__ u16 smem[2 * 128 * 64];           // As | Bs ; reused as [128][128] for V^T
    u16* As = smem;
    u16* Bs = smem + 128 * 64;
    const int m0 = blockIdx.y * 128, n0 = blockIdx.x * 128;
    const int tid = threadIdx.x;
    const int w = tid >> 6, lane = tid & 63, lr = lane & 15, h = lane >> 4;
    const int wr = w >> 1, wc = w & 1;
    f32x4 acc[4][4] = {};

    for (int k0 = 0; k0 < 1024; k0 += 64) {
        __syncthreads();
#pragma unroll
        for (int j = 0; j < 4; ++j) {
            int L = j * 256 + tid;
            int r = L >> 3, c = L & 7;
            int csw = (c ^ (r & 7)) << 3;
            gld16(xb + (size_t)(m0 + r) * 1024 + k0 + csw, As + L * 8);
            gld16(wT + (size_t)(n0 + r) * 1024 + k0 + csw, Bs + L * 8);
        }
        __syncthreads();
#pragma unroll
        for (int kk = 0; kk < 2; ++kk) {
            bf16x8 a[4], b[4];
            int cc = kk * 4 + h;
#pragma unroll
            for (int m = 0; m < 4; ++m) {
                int R = wr * 64 + m * 16 + lr;
                a[m] = *reinterpret_cast<const bf16x8*>((const char*)As + R * 128 + ((cc ^ (R & 7)) << 4));
            }
#pragma unroll
            for (int n = 0; n < 4; ++n) {
                int R = wc * 64 + n * 16 + lr;
                b[n] = *reinterpret_cast<const bf16x8*>((const char*)Bs + R * 128 + ((cc ^ (R & 7)) << 4));
            }
#pragma unroll
            for (int m = 0; m < 4; ++m)
#pragma unroll
                for (int n = 0; n < 4; ++n)
                    acc[m][n] = __builtin_amdgcn_mfma_f32_16x16x32_bf16(a[m], b[n], acc[m][n], 0, 0, 0);
        }
    }

    const int nthird = n0 >> 10;    // uniform per block (128 | 1024)
    if (nthird == 2) {
        // ---- V: transpose 128x128 subtile through LDS with key-permute ----
        __syncthreads();
#pragma unroll
        for (int n = 0; n < 4; ++n) {
            int nloc = wc * 64 + n * 16 + lr;
            unsigned xorv = (unsigned)(nloc & 15) << 4;
            float bv = bias[n0 + nloc];
#pragma unroll
            for (int m = 0; m < 4; ++m) {
                int mloc = wr * 64 + m * 16 + h * 4;
                // permuted position: o=16a+4h+r -> 8h+4a+r within 32-block
                int mp = (mloc & ~31) | (((mloc >> 2) & 3) << 3) | (((mloc >> 4) & 1) << 2);
                union { u16 u[4]; unsigned long long ll; } pk4;
#pragma unroll
                for (int reg = 0; reg < 4; ++reg)
                    pk4.u[reg] = f2b(acc[m][n][reg] + bv);
                *reinterpret_cast<unsigned long long*>(
                    (char*)smem + nloc * 256 + ((unsigned)(mp * 2) ^ xorv)) = pk4.ll;
            }
        }
        __syncthreads();
        const int b = m0 >> 11, t0 = m0 & 2047;
        const int c16 = tid & 15;
#pragma unroll
        for (int step = 0; step < 8; ++step) {
            int row = (tid >> 4) + step * 16;           // nloc 0..127
            ushort8 vch = *reinterpret_cast<const ushort8*>(
                (const char*)smem + row * 256 + ((unsigned)((c16 ^ (row & 15)) << 4)));
            int c1 = (n0 + row) & 1023;
            int hh = c1 >> 6, dd = c1 & 63;
            *reinterpret_cast<ushort8*>(
                vtg + ((size_t)(b * HH + hh) * DD + dd) * TB + t0 + c16 * 8) = vch;
        }
    } else {
#pragma unroll
        for (int n = 0; n < 4; ++n) {
            int ng = n0 + wc * 64 + n * 16 + lr;
            int c1 = ng & 1023;
            int hh = c1 >> 6, dd = c1 & 63;
            float bv = bias[ng];
#pragma unroll
            for (int m = 0; m < 4; ++m) {
#pragma unroll
                for (int reg = 0; reg < 4; ++reg) {
                    int mg = m0 + wr * 64 + m * 16 + h * 4 + reg;
                    int b = mg >> 11, t = mg & 2047;
                    size_t bh = (size_t)b * HH + hh;
                    float val = acc[m][n][reg] + bv;
                    if (nthird == 0) qg[(bh * TB + t) * DD + dd] = f2b(val * QSCALE);
                    else             kg[(bh * TB + t) * DD + dd] = f2b(val);
                }
            }
        }
    }
}

// ---------- flash attention: 8 waves, 128 q-rows, KVB=128, dbuf ----------
__global__ __launch_bounds__(512, 4) void attn(const u16* __restrict__ qg,
                                               const u16* __restrict__ kg,
                                               const u16* __restrict__ vtg,
                                               u16* __restrict__ ao) {
    __shared__ u16 Kt[2][KVB * 64];   // [key][d], 128B rows, XOR-swizzled
    __shared__ u16 Vt[2][64 * KVB];   // [d][key-permuted], 256B rows, XOR-swizzled
    const int bh = blockIdx.y;
    const int q0 = blockIdx.x * 128;
    const int tid = threadIdx.x, w = tid >> 6, lane = tid & 63;
    const int lr = lane & 15, h = lane >> 4;
    const u16* qb = qg + (size_t)bh * TB * DD;
    const u16* kb = kg + (size_t)bh * TB * DD;
    const u16* vb = vtg + (size_t)bh * DD * TB;

#define STAGE(buf, kbase) do {                                                          \
    _Pragma("unroll")                                                                   \
    for (int j = 0; j < 2; ++j) {                                                       \
        int L = j * 512 + tid;                                                          \
        int rk = L >> 3, ck = L & 7;                                                    \
        gld16(kb + (size_t)((kbase) + rk) * DD + ((ck ^ (rk & 7)) << 3), Kt[buf] + L * 8); \
        int rv = L >> 4, cv = L & 15;                                                   \
        gld16(vb + (size_t)rv * TB + (kbase) + ((cv ^ (rv & 15)) << 3), Vt[buf] + L * 8); \
    } } while (0)

    bf16x8 bq[2];
#pragma unroll
    for (int kk = 0; kk < 2; ++kk)
        bq[kk] = *reinterpret_cast<const bf16x8*>(qb + (size_t)(q0 + w * 16 + lr) * DD + kk * 32 + h * 8);

    f32x4 o[4] = {};          // o[ngd][reg] = O[qrow=h*4+reg][d=ngd*16+lr]
    float m_r = -1e30f;       // running max for qrow=lr (replicated across h)
    float l_r = 0.f;

    STAGE(0, 0);
    __syncthreads();
    int cur = 0;

    for (int kt = 0; kt < NT; ++kt) {
        if (kt < NT - 1) STAGE(cur ^ 1, (kt + 1) * KVB);
        const u16* ktc = Kt[cur];
        const u16* vtc = Vt[cur];

        // S^T = K Q^T : s[ng][reg] = S[key=16ng+4h+reg][qrow=lr]
        f32x4 s[8] = {};
        __builtin_amdgcn_s_setprio(1);
#pragma unroll
        for (int kk = 0; kk < 2; ++kk) {
            int cc = kk * 4 + h;
#pragma unroll
            for (int ng = 0; ng < 8; ++ng) {
                int R = ng * 16 + lr;
                bf16x8 ak = *reinterpret_cast<const bf16x8*>((const char*)ktc + R * 128 + ((cc ^ (R & 7)) << 4));
                s[ng] = __builtin_amdgcn_mfma_f32_16x16x32_bf16(ak, bq[kk], s[ng], 0, 0, 0);
            }
        }
        __builtin_amdgcn_s_setprio(0);

        // online softmax (exp2 domain), defer-max; tree reduces
        float tmx[8];
#pragma unroll
        for (int ng = 0; ng < 8; ++ng)
            tmx[ng] = fmaxf(fmaxf(s[ng][0], s[ng][1]), fmaxf(s[ng][2], s[ng][3]));
        float pm = fmaxf(fmaxf(fmaxf(tmx[0], tmx[1]), fmaxf(tmx[2], tmx[3])),
                         fmaxf(fmaxf(tmx[4], tmx[5]), fmaxf(tmx[6], tmx[7])));
        pm = fmaxf(pm, __shfl_xor(pm, 16));
        pm = fmaxf(pm, __shfl_xor(pm, 32));

        if (!__all(pm - m_r <= 8.0f)) {
            float mn = fmaxf(m_r, pm);
            float fr = __builtin_amdgcn_exp2f(m_r - mn);
            m_r = mn;
            l_r *= fr;
#pragma unroll
            for (int reg = 0; reg < 4; ++reg) {
                float fro = __shfl(fr, h * 4 + reg);
#pragma unroll
                for (int ngd = 0; ngd < 4; ++ngd)
                    o[ngd][reg] *= fro;
            }
        }

        float ps[8];
#pragma unroll
        for (int ng = 0; ng < 8; ++ng) {
            s[ng][0] = __builtin_amdgcn_exp2f(s[ng][0] - m_r);
            s[ng][1] = __builtin_amdgcn_exp2f(s[ng][1] - m_r);
            s[ng][2] = __builtin_amdgcn_exp2f(s[ng][2] - m_r);
            s[ng][3] = __builtin_amdgcn_exp2f(s[ng][3] - m_r);
            ps[ng] = (s[ng][0] + s[ng][1]) + (s[ng][2] + s[ng][3]);
        }
        float sum = ((ps[0] + ps[1]) + (ps[2] + ps[3])) + ((ps[4] + ps[5]) + (ps[6] + ps[7]));
        sum += __shfl_xor(sum, 16);
        sum += __shfl_xor(sum, 32);
        l_r += sum;

        // O += P V ; V rows are key-permuted so B-frag is one b128 per (kk,ngd)
        __builtin_amdgcn_s_setprio(1);
#pragma unroll
        for (int kk = 0; kk < 4; ++kk) {
            union { unsigned u[4]; bf16x8 v; } ap;
            ap.u[0] = cvt_pk_bf16(s[2 * kk][0], s[2 * kk][1]);
            ap.u[1] = cvt_pk_bf16(s[2 * kk][2], s[2 * kk][3]);
            ap.u[2] = cvt_pk_bf16(s[2 * kk + 1][0], s[2 * kk + 1][1]);
            ap.u[3] = cvt_pk_bf16(s[2 * kk + 1][2], s[2 * kk + 1][3]);
            int cpos = kk * 4 + h;
#pragma unroll
            for (int ngd = 0; ngd < 4; ++ngd) {
                int d = ngd * 16 + lr;
                bf16x8 bv = *reinterpret_cast<const bf16x8*>((const char*)vtc + d * 256 + ((cpos ^ (d & 15)) << 4));
                o[ngd] = __builtin_amdgcn_mfma_f32_16x16x32_bf16(ap.v, bv, o[ngd], 0, 0, 0);
            }
        }
        __builtin_amdgcn_s_setprio(0);
        __syncthreads();
        cur ^= 1;
    }
#undef STAGE

    float linv[4];
#pragma unroll
    for (int reg = 0; reg < 4; ++reg)
        linv[reg] = 1.0f / __shfl(l_r, h * 4 + reg);

    const int b = bh >> 4, hh = bh & 15;
#pragma unroll
    for (int ngd = 0; ngd < 4; ++ngd) {
#pragma unroll
        for (int reg = 0; reg < 4; ++reg) {
            int t = q0 + w * 16 + h * 4 + reg;
            int col = hh * DD + ngd * 16 + lr;
            ao[((size_t)(b * TB + t)) * CC + col] = f2b(o[ngd][reg] * linv[reg]);
        }
    }
}

// ---------- GEMM2: out = ao @ W_out + b_out, BM=64 BN=128 (2 blocks/CU) ----------
__global__ __launch_bounds__(256) void gemm_out(const u16* __restrict__ ao,   // [4096][1024]
                                                const u16* __restrict__ wT,   // [1024][1024]
                                                const float* __restrict__ bias,
                                                float* __restrict__ out) {
    __shared__ u16 As[64 * 64];
    __shared__ u16 Bs[128 * 64];
    const int m0 = blockIdx.y * 64, n0 = blockIdx.x * 128;
    const int tid = threadIdx.x;
    const int w = tid >> 6, lane = tid & 63, lr = lane & 15, h = lane >> 4;
    f32x4 acc[4][2] = {};

    for (int k0 = 0; k0 < 1024; k0 += 64) {
        __syncthreads();
#pragma unroll
        for (int j = 0; j < 2; ++j) {
            int L = j * 256 + tid;
            int r = L >> 3, c = L & 7;
            gld16(ao + (size_t)(m0 + r) * 1024 + k0 + ((c ^ (r & 7)) << 3), As + L * 8);
        }
#pragma unroll
        for (int j = 0; j < 4; ++j) {
            int L = j * 256 + tid;
            int r = L >> 3, c = L & 7;
            gld16(wT + (size_t)(n0 + r) * 1024 + k0 + ((c ^ (r & 7)) << 3), Bs + L * 8);
        }
        __syncthreads();
#pragma unroll
        for (int kk = 0; kk < 2; ++kk) {
            bf16x8 a[4], b[2];
            int cc = kk * 4 + h;
#pragma unroll
            for (int m = 0; m < 4; ++m) {
                int R = m * 16 + lr;
                a[m] = *reinterpret_cast<const bf16x8*>((const char*)As + R * 128 + ((cc ^ (R & 7)) << 4));
            }
#pragma unroll
            for (int n = 0; n < 2; ++n) {
                int R = w * 32 + n * 16 + lr;
                b[n] = *reinterpret_cast<const bf16x8*>((const char*)Bs + R * 128 + ((cc ^ (R & 7)) << 4));
            }
#pragma unroll
            for (int m = 0; m < 4; ++m)
#pragma unroll
                for (int n = 0; n < 2; ++n)
                    acc[m][n] = __builtin_amdgcn_mfma_f32_16x16x32_bf16(a[m], b[n], acc[m][n], 0, 0, 0);
        }
    }

#pragma unroll
    for (int n = 0; n < 2; ++n) {
        int ng = n0 + w * 32 + n * 16 + lr;
        float bv = bias[ng];
#pragma unroll
        for (int m = 0; m < 4; ++m) {
#pragma unroll
            for (int reg = 0; reg < 4; ++reg) {
                int mg = m0 + m * 16 + h * 4 + reg;
                out[(size_t)mg * 1024 + ng] = acc[m][n][reg] + bv;
            }
        }
    }
}

extern "C" void kernel_launch(void* const* d_in, const int* in_sizes, int n_in,
                              void* d_out, int out_size, void* d_ws, size_t ws_size,
                              hipStream_t stream) {
    const float* x     = (const float*)d_in[0];
    const float* W_qkv = (const float*)d_in[1];
    const float* b_qkv = (const float*)d_in[2];
    const float* W_out = (const float*)d_in[3];
    const float* b_out = (const float*)d_in[4];
    float* out = (float*)d_out;

    char* ws = (char*)d_ws;
    u16* xb    = (u16*)(ws);                       // 8 MB  x bf16 [4096][1024]
    u16* wqkvT = (u16*)(ws + (size_t)( 8u << 20)); // 6 MB  W_qkv^T bf16 [3072][1024]
    u16* woutT = (u16*)(ws + (size_t)(14u << 20)); // 2 MB  W_out^T bf16 [1024][1024]
    u16* qg    = (u16*)(ws + (size_t)(16u << 20)); // 8 MB  Q [B,H,T,D] (pre-scaled)
    u16* kg    = (u16*)(ws + (size_t)(24u << 20)); // 8 MB  K [B,H,T,D]
    u16* vtg   = (u16*)(ws + (size_t)(32u << 20)); // 8 MB  V^T [B,H,D,T] key-permuted
    u16* ao    = xb;                               // reuse x buffer for attn-out

    hipLaunchKernelGGL(cvt_bf16, dim3(4096), dim3(256), 0, stream, x, xb, MM * CC);
    hipLaunchKernelGGL(transpose_cvt2, dim3(64, 16), dim3(256), 0, stream, W_qkv, wqkvT, W_out, woutT);
    hipLaunchKernelGGL(gemm_qkv, dim3(24, 32), dim3(256), 0, stream, xb, wqkvT, b_qkv, qg, kg, vtg);
    hipLaunchKernelGGL(attn, dim3(16, 32), dim3(512), 0, stream, qg, kg, vtg, ao);
    hipLaunchKernelGGL(gemm_out, dim3(8, 64), dim3(256), 0, stream, ao, woutT, b_out, out);
}